// Round 1
// baseline (19.239 us; speedup 1.0000x reference)
//
#include <hip/hip_runtime.h>
#include <math.h>

#define N      8192
#define IBLK   256
#define JBLK   256
#define NI     (N / IBLK)   // 32 i-chunks
#define NJ     (N / JBLK)   // 32 j-chunks

// ws layout: [0 .. N) = risk_sum accumulator (float)
__global__ __launch_bounds__(256) void cox_zero_ws(float* __restrict__ ws) {
    int i = blockIdx.x * 256 + threadIdx.x;
    if (i < N) ws[i] = 0.0f;
}

// Partial risk sums: block (bi, bj) accumulates j-chunk bj into risk[i] for
// i in chunk bi. LDS-staged j values, wave-uniform broadcast reads.
__global__ __launch_bounds__(256) void cox_risk_partial(
        const float* __restrict__ logRR,
        const float* __restrict__ ytime,
        float* __restrict__ risk) {
    __shared__ float s_yt[JBLK];
    __shared__ float s_et[JBLK];

    const int tid = threadIdx.x;
    const int bi  = blockIdx.x & (NI - 1);   // i-chunk
    const int bj  = blockIdx.x >> 5;         // j-chunk (NI == 32)
    const int jbase = bj * JBLK;

    s_yt[tid] = ytime[jbase + tid];
    s_et[tid] = expf(logRR[jbase + tid]);
    __syncthreads();

    const int   i   = bi * IBLK + tid;
    const float yti = ytime[i];

    const float4* yt4 = reinterpret_cast<const float4*>(s_yt);
    const float4* et4 = reinterpret_cast<const float4*>(s_et);

    float s0 = 0.f, s1 = 0.f, s2 = 0.f, s3 = 0.f;
#pragma unroll
    for (int j = 0; j < JBLK / 4; ++j) {
        float4 yt = yt4[j];
        float4 et = et4[j];
        s0 += (yt.x >= yti) ? et.x : 0.f;
        s1 += (yt.y >= yti) ? et.y : 0.f;
        s2 += (yt.z >= yti) ? et.z : 0.f;
        s3 += (yt.w >= yti) ? et.w : 0.f;
    }
    atomicAdd(&risk[i], (s0 + s1) + (s2 + s3));
}

// Single-block finalize: val_i = (theta_i - log(risk_i)) * ystatus_i,
// reduce over all i, write -mean to out[0].
__global__ __launch_bounds__(1024) void cox_finalize(
        const float* __restrict__ logRR,
        const float* __restrict__ ystatus,
        const float* __restrict__ risk,
        float* __restrict__ out) {
    const int tid = threadIdx.x;

    float acc = 0.f;
    for (int i = tid; i < N; i += 1024) {
        acc += (logRR[i] - logf(risk[i])) * ystatus[i];
    }

    // wave (64-lane) reduction
    for (int off = 32; off > 0; off >>= 1)
        acc += __shfl_down(acc, off);

    __shared__ float red[16];   // 1024 / 64 waves
    const int wave = tid >> 6;
    const int lane = tid & 63;
    if (lane == 0) red[wave] = acc;
    __syncthreads();

    if (tid == 0) {
        float s = 0.f;
#pragma unroll
        for (int w = 0; w < 16; ++w) s += red[w];
        out[0] = -s / (float)N;
    }
}

extern "C" void kernel_launch(void* const* d_in, const int* in_sizes, int n_in,
                              void* d_out, int out_size, void* d_ws, size_t ws_size,
                              hipStream_t stream) {
    const float* logRR   = (const float*)d_in[0];
    const float* ytime   = (const float*)d_in[1];
    const float* ystatus = (const float*)d_in[2];
    float* out  = (float*)d_out;
    float* risk = (float*)d_ws;

    cox_zero_ws<<<NI, 256, 0, stream>>>(risk);
    cox_risk_partial<<<NI * NJ, 256, 0, stream>>>(logRR, ytime, risk);
    cox_finalize<<<1, 1024, 0, stream>>>(logRR, ystatus, risk, out);
}

// Round 2
// 16.198 us; speedup vs baseline: 1.1877x; 1.1877x over previous
//
#include <hip/hip_runtime.h>
#include <math.h>

#define N        8192
#define NBLK     512      // K1 grid
#define THREADS  256
#define IPB      16       // i rows per block
#define SLICES   16       // j-slices per block (THREADS / IPB)
#define G4       (N / 4)  // float4 groups over j

// K1: block b computes complete risk_sum for i in [b*16, b*16+16), plus the
// block's loss partial -> ws[b]. All j staged in LDS (ytime + exp(theta)),
// computed in-block. Wave layout: lane = (slice<<4) | i_local, so each
// wave-read touches 4 consecutive float4s broadcast across 16-lane groups.
__global__ __launch_bounds__(THREADS, 2) void cox_fused(
        const float* __restrict__ logRR,
        const float* __restrict__ ytime,
        const float* __restrict__ ystatus,
        float* __restrict__ ws) {
    __shared__ float s_yt[N];
    __shared__ float s_et[N];
    __shared__ float s_red[THREADS];

    const int tid = threadIdx.x;
    const int b   = blockIdx.x;

    // Stage all 8192 j-values: ytime and exp(logRR), float4-vectorized.
    const float4* ytg = reinterpret_cast<const float4*>(ytime);
    const float4* thg = reinterpret_cast<const float4*>(logRR);
    float4* syt = reinterpret_cast<float4*>(s_yt);
    float4* set = reinterpret_cast<float4*>(s_et);
#pragma unroll
    for (int k = 0; k < G4 / THREADS; ++k) {   // 8 iters
        int idx = k * THREADS + tid;
        float4 y = ytg[idx];
        float4 t = thg[idx];
        syt[idx] = y;
        float4 e;
        e.x = __expf(t.x); e.y = __expf(t.y);
        e.z = __expf(t.z); e.w = __expf(t.w);
        set[idx] = e;
    }
    __syncthreads();

    const int il = tid & (IPB - 1);    // i within block
    const int sl = tid >> 4;           // j-slice 0..15
    const float yti = ytime[b * IPB + il];

    float s0 = 0.f, s1 = 0.f, s2 = 0.f, s3 = 0.f;
#pragma unroll 8
    for (int m = 0; m < G4 / SLICES; ++m) {    // 128 iters of 4 j's
        int jg = m * SLICES + sl;
        float4 yt = syt[jg];
        float4 et = set[jg];
        s0 += (yt.x >= yti) ? et.x : 0.f;
        s1 += (yt.y >= yti) ? et.y : 0.f;
        s2 += (yt.z >= yti) ? et.z : 0.f;
        s3 += (yt.w >= yti) ? et.w : 0.f;
    }
    s_red[tid] = (s0 + s1) + (s2 + s3);
    __syncthreads();

    // 16 lanes: combine 16 slice-partials per i, compute loss term, reduce.
    if (tid < IPB) {
        float risk = 0.f;
#pragma unroll
        for (int k = 0; k < SLICES; ++k) risk += s_red[k * IPB + tid];
        const int i = b * IPB + tid;
        float lv = (logRR[i] - logf(risk)) * ystatus[i];
#pragma unroll
        for (int off = 8; off; off >>= 1) lv += __shfl_down(lv, off, 16);
        if (tid == 0) ws[b] = lv;
    }
}

// K2: reduce 512 block partials -> scalar loss.
__global__ __launch_bounds__(512) void cox_final(
        const float* __restrict__ ws, float* __restrict__ out) {
    const int tid = threadIdx.x;
    float v = ws[tid];
#pragma unroll
    for (int off = 32; off; off >>= 1) v += __shfl_down(v, off);
    __shared__ float red[8];
    if ((tid & 63) == 0) red[tid >> 6] = v;
    __syncthreads();
    if (tid == 0) {
        float s = 0.f;
#pragma unroll
        for (int w = 0; w < 8; ++w) s += red[w];
        out[0] = -s / (float)N;
    }
}

extern "C" void kernel_launch(void* const* d_in, const int* in_sizes, int n_in,
                              void* d_out, int out_size, void* d_ws, size_t ws_size,
                              hipStream_t stream) {
    const float* logRR   = (const float*)d_in[0];
    const float* ytime   = (const float*)d_in[1];
    const float* ystatus = (const float*)d_in[2];
    float* out = (float*)d_out;
    float* ws  = (float*)d_ws;

    cox_fused<<<NBLK, THREADS, 0, stream>>>(logRR, ytime, ystatus, ws);
    cox_final<<<1, 512, 0, stream>>>(ws, out);
}

// Round 3
// 15.138 us; speedup vs baseline: 1.2709x; 1.0700x over previous
//
#include <hip/hip_runtime.h>
#include <math.h>

#define N        8192
#define NBLK     512            // K1 grid: 2 blocks/CU
#define THREADS  256
#define IPB      16             // i rows per block
#define R        8              // i rows per THREAD (register tile)
#define ITH      (IPB / R)      // 2 i-thread groups
#define SLICES   (THREADS / ITH)// 128 j-slices
#define G4       (N / 4)        // 2048 float4 groups over j
#define MITER    (G4 / SLICES)  // 16 main-loop iterations

// K1: block b computes complete risk_sum for i in [b*16, b*16+16) with an
// 8-row register tile per thread (each LDS read reused for 8 i's), then the
// block's loss partial -> ws[b].
__global__ __launch_bounds__(THREADS, 2) void cox_fused(
        const float* __restrict__ logRR,
        const float* __restrict__ ytime,
        const float* __restrict__ ystatus,
        float* __restrict__ ws) {
    __shared__ float s_yt[N];
    __shared__ float s_et[N];
    __shared__ float s_red[(THREADS / 64) * ITH * R];   // 64 floats

    const int tid = threadIdx.x;
    const int b   = blockIdx.x;

    // Stage all 8192 j-values: ytime and exp(logRR), float4-vectorized.
    const float4* ytg = reinterpret_cast<const float4*>(ytime);
    const float4* thg = reinterpret_cast<const float4*>(logRR);
    float4* syt = reinterpret_cast<float4*>(s_yt);
    float4* set = reinterpret_cast<float4*>(s_et);
#pragma unroll
    for (int k = 0; k < G4 / THREADS; ++k) {   // 8 iters
        int idx = k * THREADS + tid;
        float4 y = ytg[idx];
        float4 t = thg[idx];
        syt[idx] = y;
        float4 e;
        e.x = __expf(t.x); e.y = __expf(t.y);
        e.z = __expf(t.z); e.w = __expf(t.w);
        set[idx] = e;
    }
    __syncthreads();

    const int it = tid & (ITH - 1);     // i-thread group 0..1
    const int sl = tid >> 1;            // j-slice 0..127

    float yti[R];
#pragma unroll
    for (int r = 0; r < R; ++r) yti[r] = ytime[b * IPB + it * R + r];

    float acc[R][2] = {};
#pragma unroll 4
    for (int m = 0; m < MITER; ++m) {   // 16 iters of 4 j's x 8 i's
        int jg = m * SLICES + sl;
        float4 yt = syt[jg];
        float4 et = set[jg];
#pragma unroll
        for (int r = 0; r < R; ++r) {
            float a0 = acc[r][0], a1 = acc[r][1];
            a0 += (yt.x >= yti[r]) ? et.x : 0.f;
            a1 += (yt.y >= yti[r]) ? et.y : 0.f;
            a0 += (yt.z >= yti[r]) ? et.z : 0.f;
            a1 += (yt.w >= yti[r]) ? et.w : 0.f;
            acc[r][0] = a0; acc[r][1] = a1;
        }
    }

    // Reduce over the 32 slices within each wave (lane^2.. keeps it-group).
    const int wave = tid >> 6;
    const int lane = tid & 63;
    float red[R];
#pragma unroll
    for (int r = 0; r < R; ++r) {
        float v = acc[r][0] + acc[r][1];
        v += __shfl_xor(v, 2);
        v += __shfl_xor(v, 4);
        v += __shfl_xor(v, 8);
        v += __shfl_xor(v, 16);
        v += __shfl_xor(v, 32);
        red[r] = v;
    }
    if (lane < ITH) {
#pragma unroll
        for (int r = 0; r < R; ++r)
            s_red[(wave * ITH + lane) * R + r] = red[r];
    }
    __syncthreads();

    // 16 lanes: combine 4 wave-partials per i, loss term, 16-lane reduce.
    if (tid < IPB) {
        const int itl = tid >> 3;       // i_local = it*8 + r
        const int rl  = tid & 7;
        float risk = 0.f;
#pragma unroll
        for (int w = 0; w < THREADS / 64; ++w)
            risk += s_red[(w * ITH + itl) * R + rl];
        const int i = b * IPB + tid;
        float lv = (logRR[i] - __logf(risk)) * ystatus[i];
#pragma unroll
        for (int off = 8; off; off >>= 1) lv += __shfl_down(lv, off, 16);
        if (tid == 0) ws[b] = lv;
    }
}

// K2: reduce 512 block partials -> scalar loss.
__global__ __launch_bounds__(512) void cox_final(
        const float* __restrict__ ws, float* __restrict__ out) {
    const int tid = threadIdx.x;
    float v = ws[tid];
#pragma unroll
    for (int off = 32; off; off >>= 1) v += __shfl_down(v, off);
    __shared__ float red[8];
    if ((tid & 63) == 0) red[tid >> 6] = v;
    __syncthreads();
    if (tid == 0) {
        float s = 0.f;
#pragma unroll
        for (int w = 0; w < 8; ++w) s += red[w];
        out[0] = -s / (float)N;
    }
}

extern "C" void kernel_launch(void* const* d_in, const int* in_sizes, int n_in,
                              void* d_out, int out_size, void* d_ws, size_t ws_size,
                              hipStream_t stream) {
    const float* logRR   = (const float*)d_in[0];
    const float* ytime   = (const float*)d_in[1];
    const float* ystatus = (const float*)d_in[2];
    float* out = (float*)d_out;
    float* ws  = (float*)d_ws;

    cox_fused<<<NBLK, THREADS, 0, stream>>>(logRR, ytime, ystatus, ws);
    cox_final<<<1, 512, 0, stream>>>(ws, out);
}